// Round 7
// baseline (309.676 us; speedup 1.0000x reference)
//
#include <hip/hip_runtime.h>
#include <cstdint>
#include <cstddef>

#define IN_F 4096
#define OUT_F 4096
#define NROWS 8192
#define BM 256
#define BN 256
#define BK 32
#define NT (IN_F / BK)   // 128 K-tiles

typedef float f32x4 __attribute__((ext_vector_type(4)));
typedef short s16x8 __attribute__((ext_vector_type(8)));

// round-to-nearest-even fp32 -> bf16
__device__ inline unsigned short f2bf_rne(float f) {
    unsigned int u = __float_as_uint(f);
    u += 0x7FFFu + ((u >> 16) & 1u);
    return (unsigned short)(u >> 16);
}

// Fused: blocks [0, 8192) build W; blocks [8192, 24576) convert x to bf16.
// w[o][t] = 2*norm(o)*sin(pi*(o+1)*(2t+1)/8192); integer-exact reduction mod 16384.
__global__ void prep(const float* __restrict__ x, const float* __restrict__ fc,
                     unsigned short* __restrict__ wb, unsigned short* __restrict__ xb) {
    const int b = blockIdx.x;
    if (b < OUT_F * IN_F / 8 / 256) {
        int gid = b * 256 + threadIdx.x;
        int o = gid >> 9;
        int t0 = (gid & 511) << 3;
        int k = (int)fc[o];
        float amp = 2.0f * rsqrtf(2.0f * (float)IN_F * ((k == 0) ? 2.0f : 1.0f));
        unsigned int op1 = (unsigned int)(k + 1);
        union { s16x8 v; unsigned short s[8]; } p;
#pragma unroll
        for (int j = 0; j < 8; ++j) {
            unsigned int t = (unsigned int)(t0 + j);
            unsigned int r = (op1 * (2u * t + 1u)) & 16383u;
            float ang = (float)r * 3.83495196971410293e-4f;  // pi/8192
            p.s[j] = f2bf_rne(amp * __sinf(ang));
        }
        *reinterpret_cast<s16x8*>(&wb[(size_t)gid * 8]) = p.v;
    } else {
        size_t gid = (size_t)(b - OUT_F * IN_F / 8 / 256) * 256 + threadIdx.x;
        const f32x4* xv = reinterpret_cast<const f32x4*>(x) + gid * 2;
        f32x4 a = xv[0], c = xv[1];
        union { s16x8 v; unsigned short s[8]; } p;
        p.s[0] = f2bf_rne(a[0]); p.s[1] = f2bf_rne(a[1]);
        p.s[2] = f2bf_rne(a[2]); p.s[3] = f2bf_rne(a[3]);
        p.s[4] = f2bf_rne(c[0]); p.s[5] = f2bf_rne(c[1]);
        p.s[6] = f2bf_rne(c[2]); p.s[7] = f2bf_rne(c[3]);
        *reinterpret_cast<s16x8*>(&xb[gid * 8]) = p.v;
    }
}

__device__ inline void wg_barrier() {
    asm volatile("" ::: "memory");
    __builtin_amdgcn_s_barrier();
    asm volatile("" ::: "memory");
}

#define GLD(gsrc, ldst) __builtin_amdgcn_global_load_lds( \
    (const __attribute__((address_space(1))) unsigned int*)(gsrc), \
    (__attribute__((address_space(3))) unsigned int*)(ldst), 16, 0, 0)

// Stage A/B K-tile T into buf[T&3]. 256 threads x 4 GLD = 16KB each.
// Proven 0-conflict layout: granule g holds (row=g>>2, kchunk=(g&3)^((g>>3)&3)).
#define STAGE_A(T) do { \
    char* _d = (char*)lds + (((T) & 3) << 15) + tid * 16; \
    const unsigned short* _s = gA + (size_t)(T) * BK; \
    GLD(_s,                       _d); \
    GLD(_s + (size_t)64 * IN_F,  _d + 4096); \
    GLD(_s + (size_t)128 * IN_F, _d + 8192); \
    GLD(_s + (size_t)192 * IN_F, _d + 12288); \
} while (0)

#define STAGE_B(T) do { \
    char* _d = (char*)lds + (((T) & 3) << 15) + 16384 + tid * 16; \
    const unsigned short* _s = gB + (size_t)(T) * BK; \
    GLD(_s,                       _d); \
    GLD(_s + (size_t)64 * IN_F,  _d + 4096); \
    GLD(_s + (size_t)128 * IN_F, _d + 8192); \
    GLD(_s + (size_t)192 * IN_F, _d + 12288); \
} while (0)

#define MFMA1(d, a, b) d = __builtin_amdgcn_mfma_f32_16x16x32_bf16(a, b, d, 0, 0, 0)

// Software-pipelined K-tile: stage(t+3); counted vmcnt (retires stage t+1);
// lgkm-drain (completes CUR reads, issued last tile; WAR-safety for the
// barrier); barrier; prefetch frags(t+1) -> NXT; 64 MFMA on CUR (hides the
// prefetch latency). One barrier per tile; vmcnt never 0 in steady state.
#define TILE(T, CUR, NXT, DO_STAGE, DO_READ, VM) do { \
    if (DO_STAGE) { STAGE_A((T) + 3); STAGE_B((T) + 3); } \
    asm volatile("s_waitcnt vmcnt(" #VM ")" ::: "memory"); \
    asm volatile("s_waitcnt lgkmcnt(0)" ::: "memory"); \
    __builtin_amdgcn_sched_barrier(0); \
    wg_barrier(); \
    if (DO_READ) { \
        const char* _nb = (const char*)lds + ((((T) + 1) & 3) << 15); \
        _Pragma("unroll") \
        for (int m = 0; m < 8; ++m) NXT##a[m] = *(const s16x8*)(_nb + aoff + m * 1024); \
        _Pragma("unroll") \
        for (int n = 0; n < 8; ++n) NXT##b[n] = *(const s16x8*)(_nb + boff + n * 1024); \
    } \
    __builtin_amdgcn_sched_barrier(0); \
    _Pragma("unroll") \
    for (int m = 0; m < 8; ++m) { \
        _Pragma("unroll") \
        for (int n = 0; n < 8; ++n) MFMA1(acc[m][n], CUR##a[m], CUR##b[n]); \
    } \
} while (0)

__global__ __launch_bounds__(256, 1) void gemm_dst(
        const unsigned short* __restrict__ xb, const unsigned short* __restrict__ wb,
        const float* __restrict__ bias, float* __restrict__ out) {
    // 4-deep circular buffer: [buf][A 16KB | B 16KB] = 128 KB
    __shared__ unsigned short lds[65536];

    const int tid = threadIdx.x;
    const int lane = tid & 63;
    const int wave = tid >> 6;
    const int wave_m = wave >> 1;   // 0..1 -> 128-row half
    const int wave_n = wave & 1;    // 0..1 -> 128-col half
    const int lr = lane & 15;
    const int kq = lane >> 4;

    const int bid = blockIdx.x;
    // XCD swizzle: 512 wgs, 64 per XCD; 16 consecutive share the A row-panel
    const int swz = (bid & 7) * 64 + (bid >> 3);
    const int brow = (swz >> 4) * BM;   // 32 row panels
    const int bcol = (swz & 15) * BN;   // 16 col panels

    // ---- stage addressing (0-conflict proven): thread tid, GLD j ->
    // row = j*64 + (tid>>2), kchunk = (tid&3)^((tid>>3)&3) ----
    const int srow = tid >> 2;
    const int skq = (tid & 3) ^ ((tid >> 3) & 3);
    const unsigned short* gA = xb + (size_t)(brow + srow) * IN_F + skq * 8;
    const unsigned short* gB = wb + (size_t)(bcol + srow) * IN_F + skq * 8;

    // ---- ds_read addressing (0-conflict proven): row R -> byte
    // R*64 + ((kq ^ ((R>>1)&3))<<4) ----
    const int colsw = ((kq ^ ((lr >> 1) & 3)) << 4);
    const int aoff = (wave_m * 128 + lr) * 64 + colsw;           // + m*1024
    const int boff = 16384 + (wave_n * 128 + lr) * 64 + colsw;   // + n*1024

    f32x4 acc[8][8];
#pragma unroll
    for (int m = 0; m < 8; ++m)
#pragma unroll
        for (int n = 0; n < 8; ++n)
            acc[m][n] = (f32x4){0.f, 0.f, 0.f, 0.f};

    // Two named fragment sets (static indexing only), alternated per tile.
    s16x8 F0a[8], F0b[8], F1a[8], F1b[8];

    // ---- prologue: stage 0,1,2; retire 0; read frags(0) -> F0 ----
    STAGE_A(0); STAGE_B(0);
    STAGE_A(1); STAGE_B(1);
    STAGE_A(2); STAGE_B(2);
    asm volatile("s_waitcnt vmcnt(16)" ::: "memory");
    wg_barrier();
#pragma unroll
    for (int m = 0; m < 8; ++m) F0a[m] = *(const s16x8*)((const char*)lds + aoff + m * 1024);
#pragma unroll
    for (int n = 0; n < 8; ++n) F0b[n] = *(const s16x8*)((const char*)lds + boff + n * 1024);

    // ---- main loop: t even -> compute F0, prefetch F1; odd -> swap ----
    for (int t = 0; t < 124; t += 2) {
        TILE(t,     F0, F1, 1, 1, 16);
        TILE(t + 1, F1, F0, 1, 1, 16);
    }
    // ---- tail: stages done at 127; drain 16 -> 8 -> 0 ----
    TILE(124, F0, F1, 1, 1, 16);   // stages 127, reads 125
    TILE(125, F1, F0, 0, 1, 8);    // reads 126
    TILE(126, F0, F1, 0, 1, 0);    // reads 127
    TILE(127, F1, F0, 0, 0, 0);    // compute only

    // ---- epilogue: C = acc + bias; 16x16 D layout: col=lane&15, row=(lane>>4)*4+j ----
    const int ccol0 = bcol + wave_n * 128 + lr;
    const int crow0 = brow + wave_m * 128 + kq * 4;
    float bv[8];
#pragma unroll
    for (int n = 0; n < 8; ++n) bv[n] = bias[ccol0 + n * 16];
#pragma unroll
    for (int m = 0; m < 8; ++m) {
#pragma unroll
        for (int j = 0; j < 4; ++j) {
            float* orow = out + (size_t)(crow0 + m * 16 + j) * OUT_F + ccol0;
#pragma unroll
            for (int n = 0; n < 8; ++n)
                orow[n * 16] = acc[m][n][j] + bv[n];
        }
    }
}

// last-resort fallback if workspace is too small (naive on-the-fly DST)
__global__ void fallback_kernel(const float* __restrict__ x, const float* __restrict__ fc,
                                const float* __restrict__ bias, float* __restrict__ out) {
    __shared__ float xrow[IN_F];
    const int o = blockIdx.x * 256 + threadIdx.x;
    const int n = blockIdx.y;
    for (int i = threadIdx.x; i < IN_F; i += 256)
        xrow[i] = x[(size_t)n * IN_F + i];
    __syncthreads();
    const int k = (int)fc[o];
    const float amp = 2.0f * rsqrtf(2.0f * (float)IN_F * ((k == 0) ? 2.0f : 1.0f));
    const unsigned int op1 = (unsigned int)(k + 1);
    float s = 0.f;
    for (int t = 0; t < IN_F; ++t) {
        unsigned int r = (op1 * (2u * (unsigned int)t + 1u)) & 16383u;
        s += xrow[t] * __sinf((float)r * 3.83495196971410293e-4f);
    }
    out[(size_t)n * OUT_F + o] = amp * s + bias[o];
}

extern "C" void kernel_launch(void* const* d_in, const int* in_sizes, int n_in,
                              void* d_out, int out_size, void* d_ws, size_t ws_size,
                              hipStream_t stream) {
    const float* x    = (const float*)d_in[0];
    const float* fc   = (const float*)d_in[1];
    const float* bias = (const float*)d_in[2];
    float* out = (float*)d_out;

    const size_t WBYTES = (size_t)OUT_F * IN_F * 2;   // 32 MB
    const size_t XBYTES = (size_t)NROWS * IN_F * 2;   // 64 MB

    if (ws_size >= WBYTES + XBYTES) {
        unsigned short* wb = (unsigned short*)d_ws;
        unsigned short* xb = (unsigned short*)((char*)d_ws + WBYTES);
        const int wgrid = OUT_F * IN_F / 8 / 256;           // 8192
        const int xgrid = NROWS * IN_F / 8 / 256;           // 16384
        prep<<<wgrid + xgrid, 256, 0, stream>>>(x, fc, wb, xb);
        const int grid = (NROWS / BM) * (OUT_F / BN);       // 512
        gemm_dst<<<grid, 256, 0, stream>>>(xb, wb, bias, out);
    } else {
        dim3 g(OUT_F / 256, NROWS);
        fallback_kernel<<<g, 256, 0, stream>>>(x, fc, bias, out);
    }
}

// Round 8
// 299.283 us; speedup vs baseline: 1.0347x; 1.0347x over previous
//
#include <hip/hip_runtime.h>
#include <cstdint>
#include <cstddef>

#define IN_F 4096
#define OUT_F 4096
#define NROWS 8192
#define BM 256
#define BN 128
#define BK 64
#define NT (IN_F / BK)   // 64 K-tiles

typedef float f32x4 __attribute__((ext_vector_type(4)));
typedef short s16x8 __attribute__((ext_vector_type(8)));

// round-to-nearest-even fp32 -> bf16
__device__ inline unsigned short f2bf_rne(float f) {
    unsigned int u = __float_as_uint(f);
    u += 0x7FFFu + ((u >> 16) & 1u);
    return (unsigned short)(u >> 16);
}

// Fused: blocks [0, 8192) build W; blocks [8192, 24576) convert x to bf16.
// w[o][t] = 2*norm(o)*sin(pi*(o+1)*(2t+1)/8192); integer-exact reduction mod 16384.
__global__ void prep(const float* __restrict__ x, const float* __restrict__ fc,
                     unsigned short* __restrict__ wb, unsigned short* __restrict__ xb) {
    const int b = blockIdx.x;
    if (b < OUT_F * IN_F / 8 / 256) {
        int gid = b * 256 + threadIdx.x;
        int o = gid >> 9;
        int t0 = (gid & 511) << 3;
        int k = (int)fc[o];
        float amp = 2.0f * rsqrtf(2.0f * (float)IN_F * ((k == 0) ? 2.0f : 1.0f));
        unsigned int op1 = (unsigned int)(k + 1);
        union { s16x8 v; unsigned short s[8]; } p;
#pragma unroll
        for (int j = 0; j < 8; ++j) {
            unsigned int t = (unsigned int)(t0 + j);
            unsigned int r = (op1 * (2u * t + 1u)) & 16383u;
            float ang = (float)r * 3.83495196971410293e-4f;  // pi/8192
            p.s[j] = f2bf_rne(amp * __sinf(ang));
        }
        *reinterpret_cast<s16x8*>(&wb[(size_t)gid * 8]) = p.v;
    } else {
        size_t gid = (size_t)(b - OUT_F * IN_F / 8 / 256) * 256 + threadIdx.x;
        const f32x4* xv = reinterpret_cast<const f32x4*>(x) + gid * 2;
        f32x4 a = xv[0], c = xv[1];
        union { s16x8 v; unsigned short s[8]; } p;
        p.s[0] = f2bf_rne(a[0]); p.s[1] = f2bf_rne(a[1]);
        p.s[2] = f2bf_rne(a[2]); p.s[3] = f2bf_rne(a[3]);
        p.s[4] = f2bf_rne(c[0]); p.s[5] = f2bf_rne(c[1]);
        p.s[6] = f2bf_rne(c[2]); p.s[7] = f2bf_rne(c[3]);
        *reinterpret_cast<s16x8*>(&xb[gid * 8]) = p.v;
    }
}

__device__ inline void wg_barrier() {
    asm volatile("" ::: "memory");
    __builtin_amdgcn_s_barrier();
    asm volatile("" ::: "memory");
}

#define GLD(gsrc, ldst) __builtin_amdgcn_global_load_lds( \
    (const __attribute__((address_space(1))) unsigned int*)(gsrc), \
    (__attribute__((address_space(3))) unsigned int*)(ldst), 16, 0, 0)

// Stage K-tile T (A 32KB + B 16KB) into buffer at byte SBUF. 6 GLD/thread.
// Layout: granule g holds (row = g>>3, kchunk = (g&7)^((g>>3)&7)); 128B rows.
#define STAGE(T, SBUF) do { \
    char* _d = (char*)lds + (SBUF) + tid * 16; \
    const unsigned short* _sa = gA + (size_t)(T) * BK; \
    const unsigned short* _sb = gB + (size_t)(T) * BK; \
    GLD(_sa,                        _d); \
    GLD(_sa + (size_t)64  * IN_F,   _d + 8192); \
    GLD(_sa + (size_t)128 * IN_F,   _d + 16384); \
    GLD(_sa + (size_t)192 * IN_F,   _d + 24576); \
    GLD(_sb,                        _d + 32768); \
    GLD(_sb + (size_t)64  * IN_F,   _d + 40960); \
} while (0)

#define MFMA1(d, a, b) d = __builtin_amdgcn_mfma_f32_16x16x32_bf16(a, b, d, 0, 0, 0)

// One K-tile (BK=64): 16 ds_read_b128, 6 GLD stage(t+2), 32 MFMA,
// ONE counted vmcnt + ONE barrier. Compiler schedules the interior
// (auto fine-grained lgkmcnt); waves drift between barriers -> overlap.
#define TILE(T, BUF, SBUF, DO_STAGE, VM) do { \
    const char* _bb = (const char*)lds + (BUF); \
    s16x8 A0[4], B0[4], A1[4], B1[4]; \
    _Pragma("unroll") \
    for (int m = 0; m < 4; ++m) A0[m] = *(const s16x8*)(_bb + aoff0 + m * 2048); \
    _Pragma("unroll") \
    for (int n = 0; n < 4; ++n) B0[n] = *(const s16x8*)(_bb + boff0 + n * 2048); \
    _Pragma("unroll") \
    for (int m = 0; m < 4; ++m) A1[m] = *(const s16x8*)(_bb + aoff1 + m * 2048); \
    _Pragma("unroll") \
    for (int n = 0; n < 4; ++n) B1[n] = *(const s16x8*)(_bb + boff1 + n * 2048); \
    if (DO_STAGE) STAGE((T) + 2, SBUF); \
    __builtin_amdgcn_s_setprio(1); \
    _Pragma("unroll") \
    for (int m = 0; m < 4; ++m) { \
        _Pragma("unroll") \
        for (int n = 0; n < 4; ++n) MFMA1(acc[m][n], A0[m], B0[n]); \
    } \
    _Pragma("unroll") \
    for (int m = 0; m < 4; ++m) { \
        _Pragma("unroll") \
        for (int n = 0; n < 4; ++n) MFMA1(acc[m][n], A1[m], B1[n]); \
    } \
    __builtin_amdgcn_s_setprio(0); \
    asm volatile("s_waitcnt vmcnt(" #VM ")" ::: "memory"); \
    wg_barrier(); \
} while (0)

#define B0L 0
#define B1L 49152
#define B2L 98304

__global__ __launch_bounds__(512, 1) void gemm_dst(
        const unsigned short* __restrict__ xb, const unsigned short* __restrict__ wb,
        const float* __restrict__ bias, float* __restrict__ out) {
    // 3-deep circular buffer: 3 x (A 32KB + B 16KB) = 144 KB
    __shared__ unsigned short lds[73728];

    const int tid = threadIdx.x;
    const int lane = tid & 63;
    const int wave = tid >> 6;
    const int wave_m = wave >> 1;   // 0..3 -> 64-row band
    const int wave_n = wave & 1;    // 0..1 -> 64-col half
    const int lr = lane & 15;
    const int kq = lane >> 4;

    const int bid = blockIdx.x;
    // XCD swizzle: 1024 wgs, 128 per XCD; 32 consecutive share the A row-panel
    const int swz = (bid & 7) * 128 + (bid >> 3);
    const int brow = (swz >> 5) * BM;   // 32 row panels
    const int bcol = (swz & 31) * BN;   // 32 col panels

    // ---- stage addressing: thread tid covers granule tid (+j*512); row = g>>3,
    // kchunk = (g&7) ^ ((g>>3)&7)  (pre-swizzled global source, linear LDS dest) ----
    const int srow = tid >> 3;                          // 0..63
    const int sc = (((tid & 7) ^ ((tid >> 3) & 7)) << 3);
    const unsigned short* gA = xb + (size_t)(brow + srow) * IN_F + sc;
    const unsigned short* gB = wb + (size_t)(bcol + srow) * IN_F + sc;

    // ---- ds_read addressing: row R, chunk c (=ks*4+kq) -> byte R*128 + ((c^(R&7))<<4).
    // R = wave_*64 + frag*16 + lr => R&7 = lr&7. ks=1 flips chunk bit2 -> byte^64. ----
    const int sw = ((kq ^ (lr & 7)) << 4);
    const int aoff0 = (wave_m * 64 + lr) * 128 + sw;            // + m*2048
    const int aoff1 = aoff0 ^ 64;
    const int boff0 = 98304 / 3 * 0 + 32768 + (wave_n * 64 + lr) * 128 + sw;  // + n*2048
    const int boff1 = boff0 ^ 64;

    f32x4 acc[4][4];
#pragma unroll
    for (int m = 0; m < 4; ++m)
#pragma unroll
        for (int n = 0; n < 4; ++n)
            acc[m][n] = (f32x4){0.f, 0.f, 0.f, 0.f};

    // ---- prologue: stage tiles 0,1 (12 GLD); vmcnt(6) retires tile 0 ----
    STAGE(0, B0L);
    STAGE(1, B1L);
    asm volatile("s_waitcnt vmcnt(6)" ::: "memory");
    wg_barrier();

    // ---- main loop: triple-unrolled for literal buffer bases ----
    for (int t = 0; t < 60; t += 3) {
        TILE(t,     B0L, B2L, 1, 6);
        TILE(t + 1, B1L, B0L, 1, 6);
        TILE(t + 2, B2L, B1L, 1, 6);
    }
    TILE(60, B0L, B2L, 1, 6);   // stages 62
    TILE(61, B1L, B0L, 1, 6);   // stages 63
    TILE(62, B2L, B0L, 0, 0);   // drain: retire stage 63
    TILE(63, B0L, B0L, 0, 0);

    // ---- epilogue: C = acc + bias; 16x16 D layout: col=lane&15, row=(lane>>4)*4+j ----
    const int ccol0 = bcol + wave_n * 64 + lr;
    const int crow0 = brow + wave_m * 64 + kq * 4;
    float bv[4];
#pragma unroll
    for (int n = 0; n < 4; ++n) bv[n] = bias[ccol0 + n * 16];
#pragma unroll
    for (int m = 0; m < 4; ++m) {
#pragma unroll
        for (int j = 0; j < 4; ++j) {
            float* orow = out + (size_t)(crow0 + m * 16 + j) * OUT_F + ccol0;
#pragma unroll
            for (int n = 0; n < 4; ++n)
                orow[n * 16] = acc[m][n][j] + bv[n];
        }
    }
}

// last-resort fallback if workspace is too small (naive on-the-fly DST)
__global__ void fallback_kernel(const float* __restrict__ x, const float* __restrict__ fc,
                                const float* __restrict__ bias, float* __restrict__ out) {
    __shared__ float xrow[IN_F];
    const int o = blockIdx.x * 256 + threadIdx.x;
    const int n = blockIdx.y;
    for (int i = threadIdx.x; i < IN_F; i += 256)
        xrow[i] = x[(size_t)n * IN_F + i];
    __syncthreads();
    const int k = (int)fc[o];
    const float amp = 2.0f * rsqrtf(2.0f * (float)IN_F * ((k == 0) ? 2.0f : 1.0f));
    const unsigned int op1 = (unsigned int)(k + 1);
    float s = 0.f;
    for (int t = 0; t < IN_F; ++t) {
        unsigned int r = (op1 * (2u * (unsigned int)t + 1u)) & 16383u;
        s += xrow[t] * __sinf((float)r * 3.83495196971410293e-4f);
    }
    out[(size_t)n * OUT_F + o] = amp * s + bias[o];
}

extern "C" void kernel_launch(void* const* d_in, const int* in_sizes, int n_in,
                              void* d_out, int out_size, void* d_ws, size_t ws_size,
                              hipStream_t stream) {
    const float* x    = (const float*)d_in[0];
    const float* fc   = (const float*)d_in[1];
    const float* bias = (const float*)d_in[2];
    float* out = (float*)d_out;

    const size_t WBYTES = (size_t)OUT_F * IN_F * 2;   // 32 MB
    const size_t XBYTES = (size_t)NROWS * IN_F * 2;   // 64 MB

    if (ws_size >= WBYTES + XBYTES) {
        unsigned short* wb = (unsigned short*)d_ws;
        unsigned short* xb = (unsigned short*)((char*)d_ws + WBYTES);
        const int wgrid = OUT_F * IN_F / 8 / 256;           // 8192
        const int xgrid = NROWS * IN_F / 8 / 256;           // 16384
        prep<<<wgrid + xgrid, 256, 0, stream>>>(x, fc, wb, xb);
        const int grid = (NROWS / BM) * (OUT_F / BN);       // 1024
        gemm_dst<<<grid, 512, 0, stream>>>(xb, wb, bias, out);
    } else {
        dim3 g(OUT_F / 256, NROWS);
        fallback_kernel<<<g, 256, 0, stream>>>(x, fc, bias, out);
    }
}

// Round 9
// 266.563 us; speedup vs baseline: 1.1617x; 1.1227x over previous
//
#include <hip/hip_runtime.h>
#include <cstdint>
#include <cstddef>

#define IN_F 4096
#define OUT_F 4096
#define NROWS 8192
#define BM 256
#define BN 256
#define BK 64
#define NT (IN_F / BK)   // 64 K-tiles

typedef float f32x4 __attribute__((ext_vector_type(4)));
typedef short s16x8 __attribute__((ext_vector_type(8)));

// round-to-nearest-even fp32 -> bf16
__device__ inline unsigned short f2bf_rne(float f) {
    unsigned int u = __float_as_uint(f);
    u += 0x7FFFu + ((u >> 16) & 1u);
    return (unsigned short)(u >> 16);
}

// Fused: blocks [0, 8192) build W; blocks [8192, 24576) convert x to bf16.
// w[o][t] = 2*norm(o)*sin(pi*(o+1)*(2t+1)/8192); integer-exact reduction mod 16384.
__global__ void prep(const float* __restrict__ x, const float* __restrict__ fc,
                     unsigned short* __restrict__ wb, unsigned short* __restrict__ xb) {
    const int b = blockIdx.x;
    if (b < OUT_F * IN_F / 8 / 256) {
        int gid = b * 256 + threadIdx.x;
        int o = gid >> 9;
        int t0 = (gid & 511) << 3;
        int k = (int)fc[o];
        float amp = 2.0f * rsqrtf(2.0f * (float)IN_F * ((k == 0) ? 2.0f : 1.0f));
        unsigned int op1 = (unsigned int)(k + 1);
        union { s16x8 v; unsigned short s[8]; } p;
#pragma unroll
        for (int j = 0; j < 8; ++j) {
            unsigned int t = (unsigned int)(t0 + j);
            unsigned int r = (op1 * (2u * t + 1u)) & 16383u;
            float ang = (float)r * 3.83495196971410293e-4f;  // pi/8192
            p.s[j] = f2bf_rne(amp * __sinf(ang));
        }
        *reinterpret_cast<s16x8*>(&wb[(size_t)gid * 8]) = p.v;
    } else {
        size_t gid = (size_t)(b - OUT_F * IN_F / 8 / 256) * 256 + threadIdx.x;
        const f32x4* xv = reinterpret_cast<const f32x4*>(x) + gid * 2;
        f32x4 a = xv[0], c = xv[1];
        union { s16x8 v; unsigned short s[8]; } p;
        p.s[0] = f2bf_rne(a[0]); p.s[1] = f2bf_rne(a[1]);
        p.s[2] = f2bf_rne(a[2]); p.s[3] = f2bf_rne(a[3]);
        p.s[4] = f2bf_rne(c[0]); p.s[5] = f2bf_rne(c[1]);
        p.s[6] = f2bf_rne(c[2]); p.s[7] = f2bf_rne(c[3]);
        *reinterpret_cast<s16x8*>(&xb[gid * 8]) = p.v;
    }
}

__device__ inline void wg_barrier() {
    asm volatile("" ::: "memory");
    __builtin_amdgcn_s_barrier();
    asm volatile("" ::: "memory");
}

#define GLD(gsrc, ldst) __builtin_amdgcn_global_load_lds( \
    (const __attribute__((address_space(1))) unsigned int*)(gsrc), \
    (__attribute__((address_space(3))) unsigned int*)(ldst), 16, 0, 0)

// Buffer layout (per K-tile buf d at d*65536): [Ah0|Ah1|Bh0|Bh1], each half
// 128 rows x 64 cols bf16 = 16KB, 128B rows. Granule g (16B) in a half holds
// tile element (row = g>>3, kchunk c = (g&7)^((g>>3)&7)) -- R8-proven
// 0-conflict layout (pre-swizzled global source, linear GLD dest).
#define STAGE_AH(T, H) do { \
    char* _d = (char*)lds + (((T) & 1) * 65536) + (H) * 16384 + tid * 16; \
    const unsigned short* _s = gA + (size_t)((H) * 128) * IN_F + (size_t)(T) * BK; \
    GLD(_s, _d); \
    GLD(_s + (size_t)64 * IN_F, _d + 8192); \
} while (0)

#define STAGE_BH(T, H) do { \
    char* _d = (char*)lds + (((T) & 1) * 65536) + 32768 + (H) * 16384 + tid * 16; \
    const unsigned short* _s = gB + (size_t)((H) * 128) * IN_F + (size_t)(T) * BK; \
    GLD(_s, _d); \
    GLD(_s + (size_t)64 * IN_F, _d + 8192); \
} while (0)

#define MFMA1(d, a, b) d = __builtin_amdgcn_mfma_f32_16x16x32_bf16(a, b, d, 0, 0, 0)

// read one frag pair (kstep0, kstep1) at byte offset OFF / OFF^64
#define RD2(d0, d1, OFF) do { \
    d0 = *(const s16x8*)((const char*)lds + (OFF)); \
    d1 = *(const s16x8*)((const char*)lds + ((OFF) ^ 64)); \
} while (0)

#define READS_Q00(TB) do { \
    RD2(aA0[0], aA1[0], (TB) + abase + 0 * 2048 + aswz); \
    RD2(aA0[1], aA1[1], (TB) + abase + 1 * 2048 + aswz); \
    RD2(aA0[2], aA1[2], (TB) + abase + 2 * 2048 + aswz); \
    RD2(aA0[3], aA1[3], (TB) + abase + 3 * 2048 + aswz); \
    RD2(bA0[0], bA1[0], (TB) + bbase + 0 * 2048 + aswz); \
    RD2(bA0[1], bA1[1], (TB) + bbase + 1 * 2048 + aswz); \
} while (0)

#define READS_Q01(TB) do { \
    RD2(bB0[0], bB1[0], (TB) + bbase + 2 * 2048 + aswz); \
    RD2(bB0[1], bB1[1], (TB) + bbase + 3 * 2048 + aswz); \
} while (0)

#define READS_Q10(TB) do { \
    RD2(aB0[0], aB1[0], (TB) + abase + 4 * 2048 + aswz); \
    RD2(aB0[1], aB1[1], (TB) + abase + 5 * 2048 + aswz); \
    RD2(aB0[2], aB1[2], (TB) + abase + 6 * 2048 + aswz); \
    RD2(aB0[3], aB1[3], (TB) + abase + 7 * 2048 + aswz); \
} while (0)

// 16 MFMA = one C-quadrant x K=64 (ks0 block of 8, then ks1 block; dep dist 8)
#define MFQ(MH, NH, A0v, A1v, B0v, B1v) do { \
    _Pragma("unroll") \
    for (int _m = 0; _m < 4; ++_m) { \
        MFMA1(acc[(MH) * 4 + _m][(NH) * 2 + 0], A0v[_m], B0v[0]); \
        MFMA1(acc[(MH) * 4 + _m][(NH) * 2 + 1], A0v[_m], B0v[1]); \
    } \
    _Pragma("unroll") \
    for (int _m = 0; _m < 4; ++_m) { \
        MFMA1(acc[(MH) * 4 + _m][(NH) * 2 + 0], A1v[_m], B1v[0]); \
        MFMA1(acc[(MH) * 4 + _m][(NH) * 2 + 1], A1v[_m], B1v[1]); \
    } \
} while (0)

// phase tail: barrier | lgkm drain | sched fence (rule: MFMA hoist past
// inline-asm lgkm) | setprio around MFMA cluster | closing barrier
#define PH_TAIL(MFMAS) do { \
    wg_barrier(); \
    asm volatile("s_waitcnt lgkmcnt(0)" ::: "memory"); \
    __builtin_amdgcn_sched_barrier(0); \
    __builtin_amdgcn_s_setprio(1); \
    MFMAS; \
    __builtin_amdgcn_s_setprio(0); \
    wg_barrier(); \
} while (0)

#define VMC(N) asm volatile("s_waitcnt vmcnt(" #N ")" ::: "memory")

__global__ __launch_bounds__(512, 2) void gemm_dst(
        const unsigned short* __restrict__ xb, const unsigned short* __restrict__ wb,
        const float* __restrict__ bias, float* __restrict__ out) {
    // 2 x 64KB K-tile buffers = 128 KB
    __shared__ unsigned short lds[65536];

    const int tid = threadIdx.x;
    const int lane = tid & 63;
    const int wave = tid >> 6;
    const int wave_m = wave >> 2;   // 0..1 -> 128-row half
    const int wave_n = wave & 3;    // 0..3 -> 64-col quarter
    const int lr = lane & 15;
    const int kq = lane >> 4;

    const int bid = blockIdx.x;
    // XCD swizzle: 512 wgs, 64 per XCD; 16 consecutive share the A row-panel
    const int swz = (bid & 7) * 64 + (bid >> 3);
    const int brow = (swz >> 4) * BM;   // 32 row panels
    const int bcol = (swz & 15) * BN;   // 16 col panels

    // ---- stage addressing: granule g=tid(+512): row g>>3, chunk (g&7)^((g>>3)&7)
    const int srow = tid >> 3;                              // 0..63
    const int sc = (((tid & 7) ^ ((tid >> 3) & 7)) << 3);   // src col
    const unsigned short* gA = xb + (size_t)(brow + srow) * IN_F + sc;
    const unsigned short* gB = wb + (size_t)(bcol + srow) * IN_F + sc;

    // ---- ds_read addressing (R8-proven 0-conflict): within a half, frag f
    // row = f*16+lr, chunk c = ks*4+kq -> byte f*2048 + lr*128 + ((c^(lr&7))<<4);
    // ks flips chunk bit2 -> byte^64 ----
    const int aswz = lr * 128 + ((kq ^ (lr & 7)) << 4);
    const int abase = wave_m * 16384;                                   // A half
    const int bbase = 32768 + (wave_n >> 1) * 16384 + (wave_n & 1) * 8192;  // B pos

    f32x4 acc[8][4];
#pragma unroll
    for (int m = 0; m < 8; ++m)
#pragma unroll
        for (int n = 0; n < 4; ++n)
            acc[m][n] = (f32x4){0.f, 0.f, 0.f, 0.f};

    s16x8 aA0[4], aA1[4], aB0[4], aB1[4];   // m0-3 / m4-7, ks0/ks1
    s16x8 bA0[2], bA1[2], bB0[2], bB1[2];   // n0-1 / n2-3

    // ---- prologue: T0 fully (8 GLD) + T1.Bh (4 GLD); retire T0; barrier ----
    STAGE_AH(0, 0); STAGE_AH(0, 1); STAGE_BH(0, 0); STAGE_BH(0, 1);
    STAGE_BH(1, 0); STAGE_BH(1, 1);
    VMC(4);
    wg_barrier();

    // ---- main loop: iter computes Ta=2t (buf0) + Tb=2t+1 (buf1), 8 phases ----
#pragma unroll 1
    for (int t = 0; t < 31; ++t) {
        const int Ta = 2 * t;
        // ph1..4: tile Ta from buf0
        READS_Q00(0);     STAGE_AH(Ta + 1, 0);           PH_TAIL(MFQ(0, 0, aA0, aA1, bA0, bA1));
        READS_Q01(0);     STAGE_AH(Ta + 1, 1);           PH_TAIL(MFQ(0, 1, aA0, aA1, bB0, bB1));
        READS_Q10(0);     STAGE_BH(Ta + 2, 0);           PH_TAIL(MFQ(1, 0, aB0, aB1, bA0, bA1));
                          STAGE_BH(Ta + 2, 1); VMC(4);   PH_TAIL(MFQ(1, 1, aB0, aB1, bB0, bB1));
        // ph5..8: tile Tb from buf1
        READS_Q00(65536); STAGE_AH(Ta + 2, 0);           PH_TAIL(MFQ(0, 0, aA0, aA1, bA0, bA1));
        READS_Q01(65536); STAGE_AH(Ta + 2, 1);           PH_TAIL(MFQ(0, 1, aA0, aA1, bB0, bB1));
        READS_Q10(65536); STAGE_BH(Ta + 3, 0);           PH_TAIL(MFQ(1, 0, aB0, aB1, bA0, bA1));
                          STAGE_BH(Ta + 3, 1); VMC(4);   PH_TAIL(MFQ(1, 1, aB0, aB1, bB0, bB1));
    }
    // ---- final iter: Ta=62 (buf0), Tb=63 (buf1); stage only T63.Ah; drain ----
    READS_Q00(0);     STAGE_AH(63, 0);  PH_TAIL(MFQ(0, 0, aA0, aA1, bA0, bA1));
    READS_Q01(0);     STAGE_AH(63, 1);  PH_TAIL(MFQ(0, 1, aA0, aA1, bB0, bB1));
    READS_Q10(0);                       PH_TAIL(MFQ(1, 0, aB0, aB1, bA0, bA1));
    VMC(0);                             PH_TAIL(MFQ(1, 1, aB0, aB1, bB0, bB1));
    READS_Q00(65536);                   PH_TAIL(MFQ(0, 0, aA0, aA1, bA0, bA1));
    READS_Q01(65536);                   PH_TAIL(MFQ(0, 1, aA0, aA1, bB0, bB1));
    READS_Q10(65536);                   PH_TAIL(MFQ(1, 0, aB0, aB1, bA0, bA1));
                                        PH_TAIL(MFQ(1, 1, aB0, aB1, bB0, bB1));

    // ---- epilogue: C = acc + bias; 16x16 D layout: col=lane&15, row=(lane>>4)*4+j ----
    const int ccol0 = bcol + wave_n * 64 + lr;
    const int crow0 = brow + wave_m * 128 + kq * 4;
    float bv[4];
#pragma unroll
    for (int n = 0; n < 4; ++n) bv[n] = bias[ccol0 + n * 16];
#pragma unroll
    for (int m = 0; m < 8; ++m) {
#pragma unroll
        for (int j = 0; j < 4; ++j) {
            float* orow = out + (size_t)(crow0 + m * 16 + j) * OUT_F + ccol0;
#pragma unroll
            for (int n = 0; n < 4; ++n)
                orow[n * 16] = acc[m][n][j] + bv[n];
        }
    }
}

// last-resort fallback if workspace is too small (naive on-the-fly DST)
__global__ void fallback_kernel(const float* __restrict__ x, const float* __restrict__ fc,
                                const float* __restrict__ bias, float* __restrict__ out) {
    __shared__ float xrow[IN_F];
    const int o = blockIdx.x * 256 + threadIdx.x;
    const int n = blockIdx.y;
    for (int i = threadIdx.x; i < IN_F; i += 256)
        xrow[i] = x[(size_t)n * IN_F + i];
    __syncthreads();
    const int k = (int)fc[o];
    const float amp = 2.0f * rsqrtf(2.0f * (float)IN_F * ((k == 0) ? 2.0f : 1.0f));
    const unsigned int op1 = (unsigned int)(k + 1);
    float s = 0.f;
    for (int t = 0; t < IN_F; ++t) {
        unsigned int r = (op1 * (2u * (unsigned int)t + 1u)) & 16383u;
        s += xrow[t] * __sinf((float)r * 3.83495196971410293e-4f);
    }
    out[(size_t)n * OUT_F + o] = amp * s + bias[o];
}

extern "C" void kernel_launch(void* const* d_in, const int* in_sizes, int n_in,
                              void* d_out, int out_size, void* d_ws, size_t ws_size,
                              hipStream_t stream) {
    const float* x    = (const float*)d_in[0];
    const float* fc   = (const float*)d_in[1];
    const float* bias = (const float*)d_in[2];
    float* out = (float*)d_out;

    const size_t WBYTES = (size_t)OUT_F * IN_F * 2;   // 32 MB
    const size_t XBYTES = (size_t)NROWS * IN_F * 2;   // 64 MB

    if (ws_size >= WBYTES + XBYTES) {
        unsigned short* wb = (unsigned short*)d_ws;
        unsigned short* xb = (unsigned short*)((char*)d_ws + WBYTES);
        const int wgrid = OUT_F * IN_F / 8 / 256;           // 8192
        const int xgrid = NROWS * IN_F / 8 / 256;           // 16384
        prep<<<wgrid + xgrid, 256, 0, stream>>>(x, fc, wb, xb);
        const int grid = (NROWS / BM) * (OUT_F / BN);       // 512
        gemm_dst<<<grid, 512, 0, stream>>>(xb, wb, bias, out);
    } else {
        dim3 g(OUT_F / 256, NROWS);
        fallback_kernel<<<g, 256, 0, stream>>>(x, fc, bias, out);
    }
}